// Round 1
// baseline (931.301 us; speedup 1.0000x reference)
//
#include <hip/hip_runtime.h>
#include <math.h>

#define HEADS 8
#define HID 256
#define INC 128
#define GDIM 2048  // HEADS*HID
#define NEG_SLOPE 0.2f

// ---------------- GEMM (fp32, 64x64 tile, 4x4 micro, K%32==0) ----------------
__global__ __launch_bounds__(256) void gemm_f32(
    const float* __restrict__ A, const float* __restrict__ B, float* __restrict__ C,
    int M, int Nc, int K)
{
  __shared__ float As[32][68]; // [k][row], padded; row-stride 272B (16B aligned)
  __shared__ float Bs[32][68]; // [k][col]
  int tid = threadIdx.x;
  int ty = tid >> 4, tx = tid & 15;
  int row0 = blockIdx.x * 64, col0 = blockIdx.y * 64;
  float acc[4][4] = {};
  int nk = K >> 5;
  for (int kt = 0; kt < nk; ++kt) {
    #pragma unroll
    for (int idx = tid; idx < 2048; idx += 256) {
      int r = idx >> 5, c = idx & 31;
      int gr = row0 + r;
      As[c][r] = (gr < M) ? A[(size_t)gr * K + (kt << 5) + c] : 0.f;
    }
    #pragma unroll
    for (int idx = tid; idx < 2048; idx += 256) {
      int r = idx >> 6, c = idx & 63;
      Bs[r][c] = B[(size_t)((kt << 5) + r) * Nc + col0 + c];
    }
    __syncthreads();
    #pragma unroll
    for (int k = 0; k < 32; ++k) {
      const float4 a4 = *(const float4*)&As[k][ty << 2];
      const float4 b4 = *(const float4*)&Bs[k][tx << 2];
      float a[4] = {a4.x, a4.y, a4.z, a4.w};
      float b[4] = {b4.x, b4.y, b4.z, b4.w};
      #pragma unroll
      for (int i = 0; i < 4; ++i)
        #pragma unroll
        for (int j = 0; j < 4; ++j) acc[i][j] += a[i] * b[j];
    }
    __syncthreads();
  }
  #pragma unroll
  for (int i = 0; i < 4; ++i) {
    int gr = row0 + (ty << 2) + i;
    if (gr < M) {
      #pragma unroll
      for (int j = 0; j < 4; ++j)
        C[(size_t)gr * Nc + col0 + (tx << 2) + j] = acc[i][j];
    }
  }
}

// ---------------- attention dot products a_src/a_dst [N,8] ----------------
__global__ __launch_bounds__(256) void att_dots(
    const float* __restrict__ h, const float* __restrict__ ws, const float* __restrict__ wd,
    float* __restrict__ a_src, float* __restrict__ a_dst, int N)
{
  int n = blockIdx.x, t = threadIdx.x;
  __shared__ float bufS[8][256];
  __shared__ float bufD[8][256];
  const float* hr = h + (size_t)n * GDIM;
  #pragma unroll
  for (int hd = 0; hd < 8; ++hd) {
    float v = hr[hd * 256 + t];
    bufS[hd][t] = v * ws[hd * 256 + t];
    bufD[hd][t] = v * wd[hd * 256 + t];
  }
  __syncthreads();
  int w = t >> 6, lane = t & 63;
  #pragma unroll
  for (int i = 0; i < 2; ++i) {
    int hd = w * 2 + i;
    float s1 = bufS[hd][lane] + bufS[hd][lane + 64] + bufS[hd][lane + 128] + bufS[hd][lane + 192];
    float d1 = bufD[hd][lane] + bufD[hd][lane + 64] + bufD[hd][lane + 128] + bufD[hd][lane + 192];
    #pragma unroll
    for (int off = 32; off >= 1; off >>= 1) {
      s1 += __shfl_down(s1, off);
      d1 += __shfl_down(d1, off);
    }
    if (lane == 0) { a_src[n * 8 + hd] = s1; a_dst[n * 8 + hd] = d1; }
  }
}

// ---------------- degree count ----------------
__global__ void deg_count(const int* __restrict__ ei, int* __restrict__ deg, int E)
{
  int e = blockIdx.x * 256 + threadIdx.x;
  if (e < E) atomicAdd(&deg[ei[E + e]], 1);
}

// ---------------- exclusive scan over N degrees (single block) ----------------
__global__ __launch_bounds__(256) void scan_deg(const int* __restrict__ deg, int* __restrict__ start, int N)
{
  __shared__ int sums[256];
  int t = threadIdx.x;
  int chunk = (N + 255) / 256;
  int s = 0;
  for (int i = 0; i < chunk; ++i) {
    int idx = t * chunk + i;
    if (idx < N) s += deg[idx];
  }
  sums[t] = s;
  __syncthreads();
  for (int off = 1; off < 256; off <<= 1) {
    int v = (t >= off) ? sums[t - off] : 0;
    __syncthreads();
    sums[t] += v;
    __syncthreads();
  }
  int run = (t == 0) ? 0 : sums[t - 1];
  for (int i = 0; i < chunk; ++i) {
    int idx = t * chunk + i;
    if (idx < N) { start[idx] = run; run += deg[idx]; }
  }
}

// ---------------- fill CSR buckets with edge ids ----------------
__global__ void fill_buckets(const int* __restrict__ ei, const int* __restrict__ start,
                             int* __restrict__ cursor, int* __restrict__ slot, int E)
{
  int e = blockIdx.x * 256 + threadIdx.x;
  if (e < E) {
    int n = ei[E + e];
    int p = atomicAdd(&cursor[n], 1);
    slot[start[n] + p] = e;
  }
}

// ---------------- GAT per-dst-node softmax + aggregate -> x1 ----------------
__global__ __launch_bounds__(256) void gat_aggregate(
    const float* __restrict__ h, const float* __restrict__ a_src, const float* __restrict__ a_dst,
    const int* __restrict__ ei, const int* __restrict__ start, const int* __restrict__ deg,
    const int* __restrict__ slot, const float* __restrict__ b_gat, float* __restrict__ x1,
    int N, int E)
{
  int n = blockIdx.x, t = threadIdx.x;
  __shared__ float adst[8];
  __shared__ float emax[8];
  __shared__ float esum[8];
  __shared__ float red[256];
  __shared__ float alpha8[8];
  int cnt = deg[n];
  int base = start[n];
  if (t < 8) adst[t] = a_dst[n * 8 + t];
  __syncthreads();
  int hd = t & 7, lj = t >> 3;
  // phase A: per-head max
  float m = -1e30f;
  for (int j = lj; j < cnt; j += 32) {
    int e = slot[base + j];
    int s = ei[e];
    float v = a_src[s * 8 + hd] + adst[hd];
    v = v > 0.f ? v : NEG_SLOPE * v;
    m = fmaxf(m, v);
  }
  red[t] = m;
  __syncthreads();
  #pragma unroll
  for (int off = 128; off >= 8; off >>= 1) {
    if (t < off) red[t] = fmaxf(red[t], red[t + off]);
    __syncthreads();
  }
  if (t < 8) emax[t] = red[t];
  __syncthreads();
  // phase B: per-head sum of exp
  float ssum = 0.f;
  for (int j = lj; j < cnt; j += 32) {
    int e = slot[base + j];
    int s = ei[e];
    float v = a_src[s * 8 + hd] + adst[hd];
    v = v > 0.f ? v : NEG_SLOPE * v;
    ssum += expf(v - emax[hd]);
  }
  red[t] = ssum;
  __syncthreads();
  #pragma unroll
  for (int off = 128; off >= 8; off >>= 1) {
    if (t < off) red[t] += red[t + off];
    __syncthreads();
  }
  if (t < 8) esum[t] = red[t] + 1e-16f;
  __syncthreads();
  // phase C: weighted aggregate of h[src]
  float acc[8] = {0.f, 0.f, 0.f, 0.f, 0.f, 0.f, 0.f, 0.f};
  for (int j = 0; j < cnt; ++j) {
    int e = slot[base + j];
    int s = ei[e];
    if (t < 8) {
      float v = a_src[s * 8 + t] + adst[t];
      v = v > 0.f ? v : NEG_SLOPE * v;
      alpha8[t] = expf(v - emax[t]) / esum[t];
    }
    __syncthreads();
    const float* hr = h + (size_t)s * GDIM;
    #pragma unroll
    for (int hh = 0; hh < 8; ++hh) acc[hh] += hr[hh * 256 + t] * alpha8[hh];
    __syncthreads();
  }
  #pragma unroll
  for (int hh = 0; hh < 8; ++hh) {
    float o = acc[hh] + b_gat[hh * 256 + t];
    x1[(size_t)n * GDIM + hh * 256 + t] = o > 0.f ? o : 0.f;
  }
}

// ---------------- SAGE: mean-aggregate y_l[src] + y_r + bias, relu -> x2 ----------------
__global__ __launch_bounds__(256) void sage_aggregate(
    const float* __restrict__ y_l, const float* __restrict__ y_r, const int* __restrict__ ei,
    const int* __restrict__ start, const int* __restrict__ deg, const int* __restrict__ slot,
    const float* __restrict__ b_l, float* __restrict__ x2, int N, int E)
{
  int n = blockIdx.x, t = threadIdx.x;
  int cnt = deg[n];
  int base = start[n];
  float acc = 0.f;
  for (int j = 0; j < cnt; ++j) {
    int e = slot[base + j];
    int s = ei[e];
    acc += y_l[(size_t)s * HID + t];
  }
  float d = (float)cnt;
  if (d < 1.f) d = 1.f;
  float o = acc / d + y_r[(size_t)n * HID + t] + b_l[t];
  x2[(size_t)n * HID + t] = o > 0.f ? o : 0.f;
}

// ---------------- MLP head ----------------
__global__ __launch_bounds__(128) void mlp_head(
    const float* __restrict__ x2, const float* __restrict__ W1, const float* __restrict__ b1,
    const float* __restrict__ W2, const float* __restrict__ b2, float* __restrict__ out, int N)
{
  int n = blockIdx.x, t = threadIdx.x;
  __shared__ float xs[256];
  __shared__ float wsum[2];
  xs[t] = x2[(size_t)n * HID + t];
  xs[t + 128] = x2[(size_t)n * HID + t + 128];
  __syncthreads();
  float acc = b1[t];
  #pragma unroll 8
  for (int k = 0; k < 256; ++k) acc += xs[k] * W1[k * 128 + t];
  float hm = acc > 0.f ? acc : 0.f;
  float p = hm * W2[t];
  #pragma unroll
  for (int off = 32; off >= 1; off >>= 1) p += __shfl_down(p, off);
  if ((t & 63) == 0) wsum[t >> 6] = p;
  __syncthreads();
  if (t == 0) out[n] = wsum[0] + wsum[1] + b2[0];
}

extern "C" void kernel_launch(void* const* d_in, const int* in_sizes, int n_in,
                              void* d_out, int out_size, void* d_ws, size_t ws_size,
                              hipStream_t stream)
{
  const float* x       = (const float*)d_in[0];
  const int*   ei      = (const int*)d_in[1];   // [2,E] int32 per harness convention
  const float* W_gat   = (const float*)d_in[3];
  const float* att_src = (const float*)d_in[4];
  const float* att_dst = (const float*)d_in[5];
  const float* b_gat   = (const float*)d_in[6];
  const float* W_sage_l = (const float*)d_in[7];
  const float* b_sage_l = (const float*)d_in[8];
  const float* W_sage_r = (const float*)d_in[9];
  const float* W_lin1  = (const float*)d_in[10];
  const float* b_lin1  = (const float*)d_in[11];
  const float* W_lin2  = (const float*)d_in[12];
  const float* b_lin2  = (const float*)d_in[13];
  float* out = (float*)d_out;

  const int N = in_sizes[0] / INC;   // 10000
  const int E = in_sizes[1] / 2;     // 80000

  // workspace carve (fp32 elements)
  float* h      = (float*)d_ws;                 // N*2048
  float* x1     = h + (size_t)N * GDIM;         // N*2048
  float* a_src  = x1 + (size_t)N * GDIM;        // N*8
  float* a_dst  = a_src + (size_t)N * 8;        // N*8
  int*   deg    = (int*)(a_dst + (size_t)N * 8);
  int*   start  = deg + N;
  int*   cursor = start + N;
  int*   slot   = cursor + N;                   // E
  // after gat_aggregate, region of h is reused:
  float* y_l = h;                               // N*256
  float* y_r = y_l + (size_t)N * HID;           // N*256
  float* x2  = y_r + (size_t)N * HID;           // N*256

  hipMemsetAsync(deg, 0, (size_t)N * sizeof(int), stream);
  hipMemsetAsync(cursor, 0, (size_t)N * sizeof(int), stream);

  // 1) h = x @ W_gat
  {
    dim3 grid((N + 63) / 64, GDIM / 64);
    gemm_f32<<<grid, 256, 0, stream>>>(x, W_gat, h, N, GDIM, INC);
  }
  // 2) attention dots
  att_dots<<<N, 256, 0, stream>>>(h, att_src, att_dst, a_src, a_dst, N);
  // 3) CSR build
  deg_count<<<(E + 255) / 256, 256, 0, stream>>>(ei, deg, E);
  scan_deg<<<1, 256, 0, stream>>>(deg, start, N);
  fill_buckets<<<(E + 255) / 256, 256, 0, stream>>>(ei, start, cursor, slot, E);
  // 4) GAT softmax-aggregate -> x1
  gat_aggregate<<<N, 256, 0, stream>>>(h, a_src, a_dst, ei, start, deg, slot, b_gat, x1, N, E);
  // 5) y_l = x1 @ W_sage_l ; y_r = x1 @ W_sage_r   (h region reused)
  {
    dim3 grid((N + 63) / 64, HID / 64);
    gemm_f32<<<grid, 256, 0, stream>>>(x1, W_sage_l, y_l, N, HID, GDIM);
    gemm_f32<<<grid, 256, 0, stream>>>(x1, W_sage_r, y_r, N, HID, GDIM);
  }
  // 6) SAGE mean aggregate + relu -> x2
  sage_aggregate<<<N, 256, 0, stream>>>(y_l, y_r, ei, start, deg, slot, b_sage_l, x2, N, E);
  // 7) MLP head -> out
  mlp_head<<<N, 128, 0, stream>>>(x2, W_lin1, b_lin1, W_lin2, b_lin2, out, N);
}

// Round 2
// 323.399 us; speedup vs baseline: 2.8797x; 2.8797x over previous
//
#include <hip/hip_runtime.h>
#include <math.h>

#define HEADS 8
#define HID 256
#define INC 128
#define GDIM 2048  // HEADS*HID
#define NEG_SLOPE 0.2f

typedef unsigned short ushort_t;
typedef short bf16x8 __attribute__((ext_vector_type(8)));
typedef float f32x4 __attribute__((ext_vector_type(4)));

__device__ __forceinline__ ushort_t f2bf(float f) {
  union { float f; unsigned u; } v; v.f = f;
  unsigned r = (v.u + 0x7FFF + ((v.u >> 16) & 1)) >> 16;  // RTNE
  return (ushort_t)r;
}

__device__ __forceinline__ void gload_lds16(const ushort_t* g, ushort_t* l) {
  __builtin_amdgcn_global_load_lds(
      (const __attribute__((address_space(1))) unsigned int*)g,
      (__attribute__((address_space(3))) unsigned int*)l, 16, 0, 0);
}

// ---------------- fp32 -> bf16 elementwise ----------------
__global__ __launch_bounds__(256) void f32_to_bf16(
    const float* __restrict__ src, ushort_t* __restrict__ dst, int n)
{
  int i = blockIdx.x * 256 + threadIdx.x;
  if (i < n) dst[i] = f2bf(src[i]);
}

// ---------------- fp32 [R][C] -> bf16 transpose dst[(rowOff+c)*R + r] ----------------
__global__ __launch_bounds__(256) void transpose_f32_bf16(
    const float* __restrict__ src, ushort_t* __restrict__ dst, int R, int C, int rowOff)
{
  __shared__ float tile[32][33];
  int tx = threadIdx.x & 31, ty = threadIdx.x >> 5;  // ty 0..7
  int r0 = blockIdx.x * 32, c0 = blockIdx.y * 32;
  #pragma unroll
  for (int i = 0; i < 32; i += 8) {
    int r = r0 + ty + i, c = c0 + tx;
    if (r < R && c < C) tile[ty + i][tx] = src[(size_t)r * C + c];
  }
  __syncthreads();
  #pragma unroll
  for (int i = 0; i < 32; i += 8) {
    int c = c0 + ty + i, r = r0 + tx;
    if (r < R && c < C) dst[(size_t)(rowOff + c) * R + r] = f2bf(tile[tx][ty + i]);
  }
}

// ---------------- bf16 MFMA GEMM: C[M][Nc] = A[M][K] * BT[Nc][K]^T ----------------
// 128x128 tile, BK=32, 4 waves (each 64x64 = 4x4 frags of 16x16x32)
__global__ __launch_bounds__(256) void gemm_bf16(
    const ushort_t* __restrict__ A, const ushort_t* __restrict__ BT,
    float* __restrict__ C, int M, int Nc, int K)
{
  __shared__ ushort_t As[128][32];  // 8 KB, row = m, 64B per row
  __shared__ ushort_t Bs[128][32];  // 8 KB, row = n
  int tid = threadIdx.x;
  int wave = tid >> 6, lane = tid & 63;
  int row0 = blockIdx.x * 128, col0 = blockIdx.y * 128;
  int wr = (wave >> 1) * 64, wc = (wave & 1) * 64;
  int lc = lane & 15, kg = lane >> 4;

  f32x4 acc[4][4] = {};

  for (int kt = 0; kt < K; kt += 32) {
    // stage A,B: per call each wave moves 16 rows x 64B; 2 calls cover 128 rows
    #pragma unroll
    for (int c = 0; c < 2; ++c) {
      int r = c * 64 + wave * 16 + (lane >> 2);
      int ga = row0 + r; if (ga >= M) ga = M - 1;
      gload_lds16(A + (size_t)ga * K + kt + (lane & 3) * 8, &As[c * 64 + wave * 16][0]);
      int gb = col0 + r;  // Nc is multiple of 128
      gload_lds16(BT + (size_t)gb * K + kt + (lane & 3) * 8, &Bs[c * 64 + wave * 16][0]);
    }
    __syncthreads();

    bf16x8 af[4], bfr[4];
    #pragma unroll
    for (int mi = 0; mi < 4; ++mi) af[mi] = *(const bf16x8*)&As[wr + mi * 16 + lc][kg * 8];
    #pragma unroll
    for (int ni = 0; ni < 4; ++ni) bfr[ni] = *(const bf16x8*)&Bs[wc + ni * 16 + lc][kg * 8];
    #pragma unroll
    for (int mi = 0; mi < 4; ++mi)
      #pragma unroll
      for (int ni = 0; ni < 4; ++ni)
        acc[mi][ni] = __builtin_amdgcn_mfma_f32_16x16x32_bf16(af[mi], bfr[ni], acc[mi][ni], 0, 0, 0);
    __syncthreads();
  }

  // C/D layout: col = lane&15, row = (lane>>4)*4 + reg
  #pragma unroll
  for (int mi = 0; mi < 4; ++mi) {
    #pragma unroll
    for (int r = 0; r < 4; ++r) {
      int grow = row0 + wr + mi * 16 + kg * 4 + r;
      if (grow < M) {
        #pragma unroll
        for (int ni = 0; ni < 4; ++ni)
          C[(size_t)grow * Nc + col0 + wc + ni * 16 + lc] = acc[mi][ni][r];
      }
    }
  }
}

// ---------------- attention dot products a_src/a_dst [N,8] ----------------
__global__ __launch_bounds__(256) void att_dots(
    const float* __restrict__ h, const float* __restrict__ ws, const float* __restrict__ wd,
    float* __restrict__ a_src, float* __restrict__ a_dst, int N)
{
  int n = blockIdx.x, t = threadIdx.x;
  __shared__ float bufS[8][256];
  __shared__ float bufD[8][256];
  const float* hr = h + (size_t)n * GDIM;
  #pragma unroll
  for (int hd = 0; hd < 8; ++hd) {
    float v = hr[hd * 256 + t];
    bufS[hd][t] = v * ws[hd * 256 + t];
    bufD[hd][t] = v * wd[hd * 256 + t];
  }
  __syncthreads();
  int w = t >> 6, lane = t & 63;
  #pragma unroll
  for (int i = 0; i < 2; ++i) {
    int hd = w * 2 + i;
    float s1 = bufS[hd][lane] + bufS[hd][lane + 64] + bufS[hd][lane + 128] + bufS[hd][lane + 192];
    float d1 = bufD[hd][lane] + bufD[hd][lane + 64] + bufD[hd][lane + 128] + bufD[hd][lane + 192];
    #pragma unroll
    for (int off = 32; off >= 1; off >>= 1) {
      s1 += __shfl_down(s1, off);
      d1 += __shfl_down(d1, off);
    }
    if (lane == 0) { a_src[n * 8 + hd] = s1; a_dst[n * 8 + hd] = d1; }
  }
}

// ---------------- CSR build ----------------
__global__ void deg_count(const int* __restrict__ ei, int* __restrict__ deg, int E)
{
  int e = blockIdx.x * 256 + threadIdx.x;
  if (e < E) atomicAdd(&deg[ei[E + e]], 1);
}

__global__ __launch_bounds__(256) void scan_deg(const int* __restrict__ deg, int* __restrict__ start, int N)
{
  __shared__ int sums[256];
  int t = threadIdx.x;
  int chunk = (N + 255) / 256;
  int s = 0;
  for (int i = 0; i < chunk; ++i) {
    int idx = t * chunk + i;
    if (idx < N) s += deg[idx];
  }
  sums[t] = s;
  __syncthreads();
  for (int off = 1; off < 256; off <<= 1) {
    int v = (t >= off) ? sums[t - off] : 0;
    __syncthreads();
    sums[t] += v;
    __syncthreads();
  }
  int run = (t == 0) ? 0 : sums[t - 1];
  for (int i = 0; i < chunk; ++i) {
    int idx = t * chunk + i;
    if (idx < N) { start[idx] = run; run += deg[idx]; }
  }
}

__global__ void fill_buckets(const int* __restrict__ ei, const int* __restrict__ start,
                             int* __restrict__ cursor, int* __restrict__ slot, int E)
{
  int e = blockIdx.x * 256 + threadIdx.x;
  if (e < E) {
    int n = ei[E + e];
    int p = atomicAdd(&cursor[n], 1);
    slot[start[n] + p] = e;
  }
}

// ---------------- GAT per-dst softmax + aggregate -> x1 (bf16) ----------------
__global__ __launch_bounds__(256) void gat_aggregate(
    const float* __restrict__ h, const float* __restrict__ a_src, const float* __restrict__ a_dst,
    const int* __restrict__ ei, const int* __restrict__ start, const int* __restrict__ deg,
    const int* __restrict__ slot, const float* __restrict__ b_gat, ushort_t* __restrict__ x1,
    int N, int E)
{
  int n = blockIdx.x, t = threadIdx.x;
  __shared__ float adst[8];
  __shared__ float emax[8];
  __shared__ float esum[8];
  __shared__ float red[256];
  __shared__ float alpha_s[32][8];
  __shared__ int src_s[32];
  int cnt = deg[n];
  int base = start[n];
  if (t < 8) adst[t] = a_dst[n * 8 + t];
  __syncthreads();
  int hd = t & 7, lj = t >> 3;
  // phase A: per-head max
  float m = -1e30f;
  for (int j = lj; j < cnt; j += 32) {
    int s = ei[slot[base + j]];
    float v = a_src[s * 8 + hd] + adst[hd];
    v = v > 0.f ? v : NEG_SLOPE * v;
    m = fmaxf(m, v);
  }
  red[t] = m;
  __syncthreads();
  #pragma unroll
  for (int off = 128; off >= 8; off >>= 1) {
    if (t < off) red[t] = fmaxf(red[t], red[t + off]);
    __syncthreads();
  }
  if (t < 8) emax[t] = red[t];
  __syncthreads();
  // phase B: per-head sum of exp
  float ssum = 0.f;
  for (int j = lj; j < cnt; j += 32) {
    int s = ei[slot[base + j]];
    float v = a_src[s * 8 + hd] + adst[hd];
    v = v > 0.f ? v : NEG_SLOPE * v;
    ssum += expf(v - emax[hd]);
  }
  red[t] = ssum;
  __syncthreads();
  #pragma unroll
  for (int off = 128; off >= 8; off >>= 1) {
    if (t < off) red[t] += red[t + off];
    __syncthreads();
  }
  if (t < 8) esum[t] = red[t] + 1e-16f;
  __syncthreads();
  // phase C: chunked alpha precompute + aggregate (2 barriers per 32 edges)
  float acc[8] = {0.f, 0.f, 0.f, 0.f, 0.f, 0.f, 0.f, 0.f};
  for (int j0 = 0; j0 < cnt; j0 += 32) {
    int el = lj;          // 0..31
    int j = j0 + el;
    if (j < cnt) {
      int s = ei[slot[base + j]];
      if (hd == 0) src_s[el] = s;
      float v = a_src[s * 8 + hd] + adst[hd];
      v = v > 0.f ? v : NEG_SLOPE * v;
      alpha_s[el][hd] = expf(v - emax[hd]) / esum[hd];
    }
    __syncthreads();
    int lim = cnt - j0; if (lim > 32) lim = 32;
    for (int el2 = 0; el2 < lim; ++el2) {
      const float* hr = h + (size_t)src_s[el2] * GDIM;
      #pragma unroll
      for (int hh = 0; hh < 8; ++hh) acc[hh] += hr[hh * 256 + t] * alpha_s[el2][hh];
    }
    __syncthreads();
  }
  #pragma unroll
  for (int hh = 0; hh < 8; ++hh) {
    float o = acc[hh] + b_gat[hh * 256 + t];
    x1[(size_t)n * GDIM + hh * 256 + t] = f2bf(o > 0.f ? o : 0.f);
  }
}

// ---------------- SAGE: mean-aggregate y[:, :256][src] + y[:, 256:] + bias, relu -> x2 ----------------
__global__ __launch_bounds__(256) void sage_aggregate(
    const float* __restrict__ y, const int* __restrict__ ei,
    const int* __restrict__ start, const int* __restrict__ deg, const int* __restrict__ slot,
    const float* __restrict__ b_l, float* __restrict__ x2, int N, int E)
{
  int n = blockIdx.x, t = threadIdx.x;
  int cnt = deg[n];
  int base = start[n];
  float acc = 0.f;
  for (int j = 0; j < cnt; ++j) {
    int s = ei[slot[base + j]];
    acc += y[(size_t)s * 512 + t];
  }
  float d = (float)cnt;
  if (d < 1.f) d = 1.f;
  float o = acc / d + y[(size_t)n * 512 + 256 + t] + b_l[t];
  x2[(size_t)n * HID + t] = o > 0.f ? o : 0.f;
}

// ---------------- MLP head ----------------
__global__ __launch_bounds__(128) void mlp_head(
    const float* __restrict__ x2, const float* __restrict__ W1, const float* __restrict__ b1,
    const float* __restrict__ W2, const float* __restrict__ b2, float* __restrict__ out, int N)
{
  int n = blockIdx.x, t = threadIdx.x;
  __shared__ float xs[256];
  __shared__ float wsum[2];
  xs[t] = x2[(size_t)n * HID + t];
  xs[t + 128] = x2[(size_t)n * HID + t + 128];
  __syncthreads();
  float acc = b1[t];
  #pragma unroll 8
  for (int k = 0; k < 256; ++k) acc += xs[k] * W1[k * 128 + t];
  float hm = acc > 0.f ? acc : 0.f;
  float p = hm * W2[t];
  #pragma unroll
  for (int off = 32; off >= 1; off >>= 1) p += __shfl_down(p, off);
  if ((t & 63) == 0) wsum[t >> 6] = p;
  __syncthreads();
  if (t == 0) out[n] = wsum[0] + wsum[1] + b2[0];
}

extern "C" void kernel_launch(void* const* d_in, const int* in_sizes, int n_in,
                              void* d_out, int out_size, void* d_ws, size_t ws_size,
                              hipStream_t stream)
{
  const float* x        = (const float*)d_in[0];
  const int*   ei       = (const int*)d_in[1];
  const float* W_gat    = (const float*)d_in[3];
  const float* att_src  = (const float*)d_in[4];
  const float* att_dst  = (const float*)d_in[5];
  const float* b_gat    = (const float*)d_in[6];
  const float* W_sage_l = (const float*)d_in[7];
  const float* b_sage_l = (const float*)d_in[8];
  const float* W_sage_r = (const float*)d_in[9];
  const float* W_lin1   = (const float*)d_in[10];
  const float* b_lin1   = (const float*)d_in[11];
  const float* W_lin2   = (const float*)d_in[12];
  const float* b_lin2   = (const float*)d_in[13];
  float* out = (float*)d_out;

  const int N = in_sizes[0] / INC;   // 10000
  const int E = in_sizes[1] / 2;     // 80000

  // ---- workspace carve ----
  char* p = (char*)d_ws;
  float*    h     = (float*)p;            p += (size_t)N * GDIM * 4;   // 82 MB
  ushort_t* x1b   = (ushort_t*)p;         p += (size_t)N * GDIM * 2;   // 41 MB
  float*    y     = (float*)p;            p += (size_t)N * 512 * 4;    // 20.5 MB
  float*    x2    = (float*)p;            p += (size_t)N * HID * 4;    // 10 MB
  ushort_t* xb    = (ushort_t*)p;         p += (size_t)N * INC * 2;    // 2.6 MB
  ushort_t* WgatT = (ushort_t*)p;         p += (size_t)GDIM * INC * 2; // 0.5 MB
  ushort_t* WsT   = (ushort_t*)p;         p += (size_t)512 * GDIM * 2; // 2 MB
  float*    a_src = (float*)p;            p += (size_t)N * 8 * 4;
  float*    a_dst = (float*)p;            p += (size_t)N * 8 * 4;
  int*      deg   = (int*)p;              p += (size_t)N * 4;
  int*      start = (int*)p;              p += (size_t)N * 4;
  int*      cursor= (int*)p;              p += (size_t)N * 4;
  int*      slot  = (int*)p;              p += (size_t)E * 4;

  hipMemsetAsync(deg, 0, (size_t)N * sizeof(int), stream);
  hipMemsetAsync(cursor, 0, (size_t)N * sizeof(int), stream);

  // 0) bf16 conversions / weight transposes
  f32_to_bf16<<<(N * INC + 255) / 256, 256, 0, stream>>>(x, xb, N * INC);
  { dim3 g((INC + 31) / 32, (GDIM + 31) / 32);
    transpose_f32_bf16<<<g, 256, 0, stream>>>(W_gat, WgatT, INC, GDIM, 0); }
  { dim3 g((GDIM + 31) / 32, (HID + 31) / 32);
    transpose_f32_bf16<<<g, 256, 0, stream>>>(W_sage_l, WsT, GDIM, HID, 0);
    transpose_f32_bf16<<<g, 256, 0, stream>>>(W_sage_r, WsT, GDIM, HID, HID); }

  // 1) h = x @ W_gat  (fp32 out)
  { dim3 grid((N + 127) / 128, GDIM / 128);
    gemm_bf16<<<grid, 256, 0, stream>>>(xb, WgatT, h, N, GDIM, INC); }

  // 2) attention dots
  att_dots<<<N, 256, 0, stream>>>(h, att_src, att_dst, a_src, a_dst, N);

  // 3) CSR build
  deg_count<<<(E + 255) / 256, 256, 0, stream>>>(ei, deg, E);
  scan_deg<<<1, 256, 0, stream>>>(deg, start, N);
  fill_buckets<<<(E + 255) / 256, 256, 0, stream>>>(ei, start, cursor, slot, E);

  // 4) GAT softmax-aggregate -> x1 (bf16)
  gat_aggregate<<<N, 256, 0, stream>>>(h, a_src, a_dst, ei, start, deg, slot, b_gat, x1b, N, E);

  // 5) y = x1 @ [W_sage_l | W_sage_r]  (fused, Nc=512)
  { dim3 grid((N + 127) / 128, 512 / 128);
    gemm_bf16<<<grid, 256, 0, stream>>>(x1b, WsT, y, N, 512, GDIM); }

  // 6) SAGE mean aggregate + relu -> x2
  sage_aggregate<<<N, 256, 0, stream>>>(y, ei, start, deg, slot, b_sage_l, x2, N, E);

  // 7) MLP head -> out
  mlp_head<<<N, 128, 0, stream>>>(x2, W_lin1, b_lin1, W_lin2, b_lin2, out, N);
}

// Round 3
// 268.325 us; speedup vs baseline: 3.4708x; 1.2053x over previous
//
#include <hip/hip_runtime.h>
#include <math.h>

#define HEADS 8
#define HID 256
#define INC 128
#define GDIM 2048  // HEADS*HID
#define NEG_SLOPE 0.2f

typedef unsigned short ushort_t;
typedef short bf16x8 __attribute__((ext_vector_type(8)));
typedef ushort_t u16x8 __attribute__((ext_vector_type(8)));
typedef float f32x4 __attribute__((ext_vector_type(4)));

__device__ __forceinline__ ushort_t f2bf(float f) {
  union { float f; unsigned u; } v; v.f = f;
  unsigned r = (v.u + 0x7FFF + ((v.u >> 16) & 1)) >> 16;  // RTNE
  return (ushort_t)r;
}
__device__ __forceinline__ float bf2f(ushort_t u) {
  union { unsigned u; float f; } v; v.u = ((unsigned)u) << 16;
  return v.f;
}

__device__ __forceinline__ void gload_lds16(const ushort_t* g, ushort_t* l) {
  __builtin_amdgcn_global_load_lds(
      (const __attribute__((address_space(1))) unsigned int*)g,
      (__attribute__((address_space(3))) unsigned int*)l, 16, 0, 0);
}

// ---------------- fp32 -> bf16 elementwise ----------------
__global__ __launch_bounds__(256) void f32_to_bf16(
    const float* __restrict__ src, ushort_t* __restrict__ dst, int n)
{
  int i = blockIdx.x * 256 + threadIdx.x;
  if (i < n) dst[i] = f2bf(src[i]);
}

// ---------------- fp32 [R][C] -> bf16 transpose dst[(rowOff+c)*R + r] ----------------
__global__ __launch_bounds__(256) void transpose_f32_bf16(
    const float* __restrict__ src, ushort_t* __restrict__ dst, int R, int C, int rowOff)
{
  __shared__ float tile[32][33];
  int tx = threadIdx.x & 31, ty = threadIdx.x >> 5;  // ty 0..7
  int r0 = blockIdx.x * 32, c0 = blockIdx.y * 32;
  #pragma unroll
  for (int i = 0; i < 32; i += 8) {
    int r = r0 + ty + i, c = c0 + tx;
    if (r < R && c < C) tile[ty + i][tx] = src[(size_t)r * C + c];
  }
  __syncthreads();
  #pragma unroll
  for (int i = 0; i < 32; i += 8) {
    int c = c0 + ty + i, r = r0 + tx;
    if (r < R && c < C) dst[(size_t)(rowOff + c) * R + r] = f2bf(tile[tx][ty + i]);
  }
}

// ---------------- GAT GEMM: hb = bf16(x @ W_gat), fused attention dots ----------------
// 128x128 tile, BK=32, 4 waves; epilogue stores bf16 h and atomically adds
// per-(row,head) partial dots with att_src/att_dst.
__global__ __launch_bounds__(256) void gemm_gat(
    const ushort_t* __restrict__ A, const ushort_t* __restrict__ BT,
    ushort_t* __restrict__ hb, float* __restrict__ a_src, float* __restrict__ a_dst,
    const float* __restrict__ att_s, const float* __restrict__ att_d,
    int M, int Nc, int K)
{
  __shared__ ushort_t As[128][32];
  __shared__ ushort_t Bs[128][32];
  int tid = threadIdx.x;
  int wave = tid >> 6, lane = tid & 63;
  int row0 = blockIdx.x * 128, col0 = blockIdx.y * 128;
  int wr = (wave >> 1) * 64, wc = (wave & 1) * 64;
  int lc = lane & 15, kg = lane >> 4;

  f32x4 acc[4][4] = {};

  for (int kt = 0; kt < K; kt += 32) {
    #pragma unroll
    for (int c = 0; c < 2; ++c) {
      int r = c * 64 + wave * 16 + (lane >> 2);
      int ga = row0 + r; if (ga >= M) ga = M - 1;
      gload_lds16(A + (size_t)ga * K + kt + (lane & 3) * 8, &As[c * 64 + wave * 16][0]);
      int gb = col0 + r;
      gload_lds16(BT + (size_t)gb * K + kt + (lane & 3) * 8, &Bs[c * 64 + wave * 16][0]);
    }
    __syncthreads();

    bf16x8 af[4], bfr[4];
    #pragma unroll
    for (int mi = 0; mi < 4; ++mi) af[mi] = *(const bf16x8*)&As[wr + mi * 16 + lc][kg * 8];
    #pragma unroll
    for (int ni = 0; ni < 4; ++ni) bfr[ni] = *(const bf16x8*)&Bs[wc + ni * 16 + lc][kg * 8];
    #pragma unroll
    for (int mi = 0; mi < 4; ++mi)
      #pragma unroll
      for (int ni = 0; ni < 4; ++ni)
        acc[mi][ni] = __builtin_amdgcn_mfma_f32_16x16x32_bf16(af[mi], bfr[ni], acc[mi][ni], 0, 0, 0);
    __syncthreads();
  }

  // epilogue: bf16 store + attention partial dots
  int head = (col0 + wc) >> 8;  // 64-col wave range never crosses a 256-col head
  float as_v[4], ad_v[4];
  #pragma unroll
  for (int ni = 0; ni < 4; ++ni) {
    int gc = col0 + wc + ni * 16 + lc;
    as_v[ni] = att_s[gc];
    ad_v[ni] = att_d[gc];
  }
  #pragma unroll
  for (int mi = 0; mi < 4; ++mi) {
    #pragma unroll
    for (int r = 0; r < 4; ++r) {
      int grow = row0 + wr + mi * 16 + kg * 4 + r;
      float ps = 0.f, pd = 0.f;
      #pragma unroll
      for (int ni = 0; ni < 4; ++ni) {
        float v = acc[mi][ni][r];
        ps += v * as_v[ni];
        pd += v * ad_v[ni];
        if (grow < M) hb[(size_t)grow * Nc + col0 + wc + ni * 16 + lc] = f2bf(v);
      }
      #pragma unroll
      for (int off = 8; off >= 1; off >>= 1) {
        ps += __shfl_xor(ps, off);
        pd += __shfl_xor(pd, off);
      }
      if (lc == 0 && grow < M) {
        atomicAdd(&a_src[grow * 8 + head], ps);
        atomicAdd(&a_dst[grow * 8 + head], pd);
      }
    }
  }
}

// ---------------- bf16 MFMA GEMM: C[M][Nc] = A[M][K] * BT[Nc][K]^T (fp32 out) ----------------
__global__ __launch_bounds__(256) void gemm_bf16(
    const ushort_t* __restrict__ A, const ushort_t* __restrict__ BT,
    float* __restrict__ C, int M, int Nc, int K)
{
  __shared__ ushort_t As[128][32];
  __shared__ ushort_t Bs[128][32];
  int tid = threadIdx.x;
  int wave = tid >> 6, lane = tid & 63;
  int row0 = blockIdx.x * 128, col0 = blockIdx.y * 128;
  int wr = (wave >> 1) * 64, wc = (wave & 1) * 64;
  int lc = lane & 15, kg = lane >> 4;

  f32x4 acc[4][4] = {};

  for (int kt = 0; kt < K; kt += 32) {
    #pragma unroll
    for (int c = 0; c < 2; ++c) {
      int r = c * 64 + wave * 16 + (lane >> 2);
      int ga = row0 + r; if (ga >= M) ga = M - 1;
      gload_lds16(A + (size_t)ga * K + kt + (lane & 3) * 8, &As[c * 64 + wave * 16][0]);
      int gb = col0 + r;
      gload_lds16(BT + (size_t)gb * K + kt + (lane & 3) * 8, &Bs[c * 64 + wave * 16][0]);
    }
    __syncthreads();

    bf16x8 af[4], bfr[4];
    #pragma unroll
    for (int mi = 0; mi < 4; ++mi) af[mi] = *(const bf16x8*)&As[wr + mi * 16 + lc][kg * 8];
    #pragma unroll
    for (int ni = 0; ni < 4; ++ni) bfr[ni] = *(const bf16x8*)&Bs[wc + ni * 16 + lc][kg * 8];
    #pragma unroll
    for (int mi = 0; mi < 4; ++mi)
      #pragma unroll
      for (int ni = 0; ni < 4; ++ni)
        acc[mi][ni] = __builtin_amdgcn_mfma_f32_16x16x32_bf16(af[mi], bfr[ni], acc[mi][ni], 0, 0, 0);
    __syncthreads();
  }

  #pragma unroll
  for (int mi = 0; mi < 4; ++mi) {
    #pragma unroll
    for (int r = 0; r < 4; ++r) {
      int grow = row0 + wr + mi * 16 + kg * 4 + r;
      if (grow < M) {
        #pragma unroll
        for (int ni = 0; ni < 4; ++ni)
          C[(size_t)grow * Nc + col0 + wc + ni * 16 + lc] = acc[mi][ni][r];
      }
    }
  }
}

// ---------------- CSR build ----------------
__global__ void deg_count(const int* __restrict__ ei, int* __restrict__ deg, int E)
{
  int e = blockIdx.x * 256 + threadIdx.x;
  if (e < E) atomicAdd(&deg[ei[E + e]], 1);
}

__global__ __launch_bounds__(256) void scan_deg(const int* __restrict__ deg, int* __restrict__ start, int N)
{
  __shared__ int sums[256];
  int t = threadIdx.x;
  int chunk = (N + 255) / 256;
  int s = 0;
  for (int i = 0; i < chunk; ++i) {
    int idx = t * chunk + i;
    if (idx < N) s += deg[idx];
  }
  sums[t] = s;
  __syncthreads();
  for (int off = 1; off < 256; off <<= 1) {
    int v = (t >= off) ? sums[t - off] : 0;
    __syncthreads();
    sums[t] += v;
    __syncthreads();
  }
  int run = (t == 0) ? 0 : sums[t - 1];
  for (int i = 0; i < chunk; ++i) {
    int idx = t * chunk + i;
    if (idx < N) { start[idx] = run; run += deg[idx]; }
  }
}

__global__ void fill_buckets(const int* __restrict__ ei, const int* __restrict__ start,
                             int* __restrict__ cursor, int* __restrict__ slot, int E)
{
  int e = blockIdx.x * 256 + threadIdx.x;
  if (e < E) {
    int n = ei[E + e];
    int p = atomicAdd(&cursor[n], 1);
    slot[start[n] + p] = e;
  }
}

// ---------------- GAT per-dst softmax + aggregate (bf16 gather) -> x1 (bf16) ----------------
__global__ __launch_bounds__(256) void gat_aggregate(
    const ushort_t* __restrict__ hb, const float* __restrict__ a_src, const float* __restrict__ a_dst,
    const int* __restrict__ ei, const int* __restrict__ start, const int* __restrict__ deg,
    const int* __restrict__ slot, const float* __restrict__ b_gat, ushort_t* __restrict__ x1,
    int N, int E)
{
  int n = blockIdx.x, t = threadIdx.x;
  __shared__ float adst[8];
  __shared__ float emax[8];
  __shared__ float esum[8];
  __shared__ float red[256];
  __shared__ float alpha_s[32][8];
  __shared__ int src_s[32];
  int cnt = deg[n];
  int base = start[n];
  if (t < 8) adst[t] = a_dst[n * 8 + t];
  __syncthreads();
  int hd = t & 7, lj = t >> 3;
  // phase A: per-head max
  float m = -1e30f;
  for (int j = lj; j < cnt; j += 32) {
    int s = ei[slot[base + j]];
    float v = a_src[s * 8 + hd] + adst[hd];
    v = v > 0.f ? v : NEG_SLOPE * v;
    m = fmaxf(m, v);
  }
  red[t] = m;
  __syncthreads();
  #pragma unroll
  for (int off = 128; off >= 8; off >>= 1) {
    if (t < off) red[t] = fmaxf(red[t], red[t + off]);
    __syncthreads();
  }
  if (t < 8) emax[t] = red[t];
  __syncthreads();
  // phase B: per-head sum of exp
  float ssum = 0.f;
  for (int j = lj; j < cnt; j += 32) {
    int s = ei[slot[base + j]];
    float v = a_src[s * 8 + hd] + adst[hd];
    v = v > 0.f ? v : NEG_SLOPE * v;
    ssum += expf(v - emax[hd]);
  }
  red[t] = ssum;
  __syncthreads();
  #pragma unroll
  for (int off = 128; off >= 8; off >>= 1) {
    if (t < off) red[t] += red[t + off];
    __syncthreads();
  }
  if (t < 8) esum[t] = red[t] + 1e-16f;
  __syncthreads();
  // phase C: thread t owns elements [t*8, t*8+8) -> head = t>>5 constant
  int head = t >> 5;
  float acc[8] = {0.f, 0.f, 0.f, 0.f, 0.f, 0.f, 0.f, 0.f};
  for (int j0 = 0; j0 < cnt; j0 += 32) {
    int j = j0 + lj;
    if (j < cnt) {
      int s = ei[slot[base + j]];
      if (hd == 0) src_s[lj] = s;
      float v = a_src[s * 8 + hd] + adst[hd];
      v = v > 0.f ? v : NEG_SLOPE * v;
      alpha_s[lj][hd] = expf(v - emax[hd]) / esum[hd];
    }
    __syncthreads();
    int lim = cnt - j0; if (lim > 32) lim = 32;
    for (int el = 0; el < lim; ++el) {
      float al = alpha_s[el][head];
      u16x8 v = *(const u16x8*)(hb + (size_t)src_s[el] * GDIM + t * 8);
      #pragma unroll
      for (int i = 0; i < 8; ++i) acc[i] += bf2f(v[i]) * al;
    }
    __syncthreads();
  }
  u16x8 o;
  #pragma unroll
  for (int i = 0; i < 8; ++i) {
    float v = acc[i] + b_gat[t * 8 + i];
    o[i] = f2bf(v > 0.f ? v : 0.f);
  }
  *(u16x8*)(x1 + (size_t)n * GDIM + t * 8) = o;
}

// ---------------- SAGE: mean-aggregate y[:, :256][src] + y[:, 256:] + bias, relu -> x2 ----------------
// 4 nodes per block, one wave (64 lanes x float4) per node
__global__ __launch_bounds__(256) void sage_aggregate(
    const float* __restrict__ y, const int* __restrict__ ei,
    const int* __restrict__ start, const int* __restrict__ deg, const int* __restrict__ slot,
    const float* __restrict__ b_l, float* __restrict__ x2, int N, int E)
{
  int w = threadIdx.x >> 6, lane = threadIdx.x & 63;
  int n = blockIdx.x * 4 + w;
  if (n >= N) return;
  int cnt = deg[n];
  int base = start[n];
  f32x4 acc = {0.f, 0.f, 0.f, 0.f};
  for (int j = 0; j < cnt; ++j) {
    int s = ei[slot[base + j]];
    f32x4 v = *(const f32x4*)(y + (size_t)s * 512 + lane * 4);
    acc += v;
  }
  float d = (float)cnt; if (d < 1.f) d = 1.f;
  f32x4 root = *(const f32x4*)(y + (size_t)n * 512 + 256 + lane * 4);
  f32x4 b = *(const f32x4*)(b_l + lane * 4);
  f32x4 o;
  #pragma unroll
  for (int i = 0; i < 4; ++i) {
    float v = acc[i] / d + root[i] + b[i];
    o[i] = v > 0.f ? v : 0.f;
  }
  *(f32x4*)(x2 + (size_t)n * HID + lane * 4) = o;
}

// ---------------- MLP head, 16 nodes per block ----------------
__global__ __launch_bounds__(256) void mlp_head(
    const float* __restrict__ x2, const float* __restrict__ W1, const float* __restrict__ b1,
    const float* __restrict__ W2, const float* __restrict__ b2, float* __restrict__ out, int N)
{
  __shared__ float xs[16][256];   // 16 KB
  __shared__ float wred[4][8];
  int t = threadIdx.x;
  int b0 = blockIdx.x * 16;
  // load 16 rows (float4 per thread iter)
  for (int i = t; i < 16 * 64; i += 256) {
    int row = i >> 6, c4 = i & 63;
    int gr = b0 + row;
    f32x4 v = (gr < N) ? *(const f32x4*)(x2 + (size_t)gr * HID + c4 * 4)
                       : f32x4{0.f, 0.f, 0.f, 0.f};
    *(f32x4*)&xs[row][c4 * 4] = v;
  }
  __syncthreads();
  int c = t & 127, g = t >> 7;    // g in {0,1}: nodes g*8 .. g*8+7
  float acc[8];
  float bb = b1[c];
  #pragma unroll
  for (int nn = 0; nn < 8; ++nn) acc[nn] = bb;
  for (int k = 0; k < 256; ++k) {
    float w = W1[k * 128 + c];
    #pragma unroll
    for (int nn = 0; nn < 8; ++nn) acc[nn] += xs[g * 8 + nn][k] * w;
  }
  float w2 = W2[c];
  float p[8];
  #pragma unroll
  for (int nn = 0; nn < 8; ++nn) {
    float hm = acc[nn] > 0.f ? acc[nn] : 0.f;
    p[nn] = hm * w2;
  }
  // wave-level reduce (64 lanes), then combine the two waves per group
  #pragma unroll
  for (int off = 32; off >= 1; off >>= 1)
    #pragma unroll
    for (int nn = 0; nn < 8; ++nn) p[nn] += __shfl_down(p[nn], off);
  int wv = t >> 6;
  if ((t & 63) == 0) {
    #pragma unroll
    for (int nn = 0; nn < 8; ++nn) wred[wv][nn] = p[nn];
  }
  __syncthreads();
  if (t < 16) {
    int gg = t >> 3, nn = t & 7;
    int node = b0 + gg * 8 + nn;
    if (node < N)
      out[node] = wred[gg * 2][nn] + wred[gg * 2 + 1][nn] + b2[0];
  }
}

extern "C" void kernel_launch(void* const* d_in, const int* in_sizes, int n_in,
                              void* d_out, int out_size, void* d_ws, size_t ws_size,
                              hipStream_t stream)
{
  const float* x        = (const float*)d_in[0];
  const int*   ei       = (const int*)d_in[1];
  const float* W_gat    = (const float*)d_in[3];
  const float* att_src  = (const float*)d_in[4];
  const float* att_dst  = (const float*)d_in[5];
  const float* b_gat    = (const float*)d_in[6];
  const float* W_sage_l = (const float*)d_in[7];
  const float* b_sage_l = (const float*)d_in[8];
  const float* W_sage_r = (const float*)d_in[9];
  const float* W_lin1   = (const float*)d_in[10];
  const float* b_lin1   = (const float*)d_in[11];
  const float* W_lin2   = (const float*)d_in[12];
  const float* b_lin2   = (const float*)d_in[13];
  float* out = (float*)d_out;

  const int N = in_sizes[0] / INC;   // 10000
  const int E = in_sizes[1] / 2;     // 80000

  // ---- workspace carve ----
  char* p = (char*)d_ws;
  ushort_t* hb    = (ushort_t*)p;         p += (size_t)N * GDIM * 2;   // 41 MB
  ushort_t* x1b   = (ushort_t*)p;         p += (size_t)N * GDIM * 2;   // 41 MB
  float*    y     = (float*)p;            p += (size_t)N * 512 * 4;    // 20.5 MB
  float*    x2    = (float*)p;            p += (size_t)N * HID * 4;    // 10 MB
  ushort_t* xb    = (ushort_t*)p;         p += (size_t)N * INC * 2;    // 2.6 MB
  ushort_t* WgatT = (ushort_t*)p;         p += (size_t)GDIM * INC * 2; // 0.5 MB
  ushort_t* WsT   = (ushort_t*)p;         p += (size_t)512 * GDIM * 2; // 2 MB
  float*    a_src = (float*)p;            p += (size_t)N * 8 * 4;
  float*    a_dst = (float*)p;            p += (size_t)N * 8 * 4;
  int*      deg   = (int*)p;              p += (size_t)N * 4;
  int*      start = (int*)p;              p += (size_t)N * 4;
  int*      cursor= (int*)p;              p += (size_t)N * 4;
  int*      slot  = (int*)p;              p += (size_t)E * 4;

  hipMemsetAsync(deg, 0, (size_t)N * sizeof(int), stream);
  hipMemsetAsync(cursor, 0, (size_t)N * sizeof(int), stream);
  hipMemsetAsync(a_src, 0, (size_t)N * 8 * sizeof(float), stream);
  hipMemsetAsync(a_dst, 0, (size_t)N * 8 * sizeof(float), stream);

  // 0) bf16 conversions / weight transposes
  f32_to_bf16<<<(N * INC + 255) / 256, 256, 0, stream>>>(x, xb, N * INC);
  { dim3 g((INC + 31) / 32, (GDIM + 31) / 32);
    transpose_f32_bf16<<<g, 256, 0, stream>>>(W_gat, WgatT, INC, GDIM, 0); }
  { dim3 g((GDIM + 31) / 32, (HID + 31) / 32);
    transpose_f32_bf16<<<g, 256, 0, stream>>>(W_sage_l, WsT, GDIM, HID, 0);
    transpose_f32_bf16<<<g, 256, 0, stream>>>(W_sage_r, WsT, GDIM, HID, HID); }

  // CSR build (independent of GEMM)
  deg_count<<<(E + 255) / 256, 256, 0, stream>>>(ei, deg, E);
  scan_deg<<<1, 256, 0, stream>>>(deg, start, N);
  fill_buckets<<<(E + 255) / 256, 256, 0, stream>>>(ei, start, cursor, slot, E);

  // 1) hb = bf16(x @ W_gat) with fused attention dots
  { dim3 grid((N + 127) / 128, GDIM / 128);
    gemm_gat<<<grid, 256, 0, stream>>>(xb, WgatT, hb, a_src, a_dst, att_src, att_dst,
                                       N, GDIM, INC); }

  // 2) GAT softmax-aggregate -> x1 (bf16)
  gat_aggregate<<<N, 256, 0, stream>>>(hb, a_src, a_dst, ei, start, deg, slot, b_gat, x1b, N, E);

  // 3) y = x1 @ [W_sage_l | W_sage_r]  (fused, Nc=512, fp32 out)
  { dim3 grid((N + 127) / 128, 512 / 128);
    gemm_bf16<<<grid, 256, 0, stream>>>(x1b, WsT, y, N, 512, GDIM); }

  // 4) SAGE mean aggregate + relu -> x2
  sage_aggregate<<<(N + 3) / 4, 256, 0, stream>>>(y, ei, start, deg, slot, b_sage_l, x2, N, E);

  // 5) MLP head -> out
  mlp_head<<<(N + 15) / 16, 256, 0, stream>>>(x2, W_lin1, b_lin1, W_lin2, b_lin2, out, N);
}